// Round 12
// baseline (38.190 us; speedup 1.0000x reference)
//
#include <hip/hip_runtime.h>

// HierarchicalMultinomialRegression: channel-parallel fused kernel, round 12.
// = round 11 (35.9us, passing) with the LDS-pipe load cut ~2.3x.
//
// Round-11 pipe accounting: LDS unit (per-CU, shared by 4 SIMDs) carried
// ~546 cyc/wave (16 b128 GEMV + 49 b32 mm-hoist + 9 b32 rho/sd + staging)
// = ~62% busy at 97.6 waves/CU -- the dominant serialized resource above
// the ~21us HBM floor. Changes:
//  - M broadcast WITHOUT LDS: lane q<49 computes M[k=q/7][j=q%7] directly
//    from L1-cached raw_chol (7 broadcast loads + 6 adds, pre-sync, no
//    staging dep); 49 v_readlane (VALU pipe, ~23% busy, per-SIMD) move it
//    into SGPRs. s_M + its staging + 49 ds_read_b32/wave deleted.
//  - rho_all row read as 2 ds_read_b128 (stride-8-float rows, 32B aligned);
//    rho_own extracted by static cndmask chain (7 b32 + 1 b32 -> 2 b128).
// LDS/wave ~546 -> ~240 cyc. Everything else identical to round 11.
//
// Fold math (verified r11): u_t[j] = rho_j^t sd_j e0[j] + sum_s rho^{t-s} nz_s,
// lane p owns steps {p+1,p+9,p+17}, forward fold with rho^8 gaps, residual
// scale rho^{(t-p-1)&7}, 21-shfl butterfly + static select.
// No launch_bounds min-waves cap (spill lessons r2/r6/r7).
//
// Inputs: 0:X(N,64) 1:beta(64,7) 2:raw_rho(7,7) 3:raw_chol(7,7,7)
//         4:eps(B,7,20,7) 5:batter_ids 6:league_ids 7:season_ids
// Output: logits (N,8) then eps_sample (N,7), concat flat, f32.

#define NF 64
#define LDIM 7
#define TDIM 20
#define KM1 7
#define BLOCK 256
#define RPB (BLOCK / 8)   // rows per block = 32
#define BPAD 68           // betaT row stride (floats)

__device__ __forceinline__ float rlane(float x, int lane) {
    return __int_as_float(__builtin_amdgcn_readlane(__float_as_int(x), lane));
}

__global__ __launch_bounds__(BLOCK) void hmr_kernel(
    const float* __restrict__ X,
    const float* __restrict__ beta,
    const float* __restrict__ raw_rho,
    const float* __restrict__ raw_chol,
    const float* __restrict__ eps,
    const int* __restrict__ batter_ids,
    const int* __restrict__ league_ids,
    const int* __restrict__ season_ids,
    float* __restrict__ out,
    int n_total)
{
    __shared__ __align__(16) float s_betaT[8][BPAD];  // betaT[k][j] = beta[j][k]
    __shared__ __align__(16) float s_rho[LDIM * 8];   // rho[l][k], stride 8
    __shared__ float s_sd[LDIM * 8];                  // sd[l][k],  stride 8

    const int tid = threadIdx.x;

    // ---- per-lane M element + readlane broadcast (no LDS involved) ----
    // lane q<49 computes M[k][j] = sum_i chol[k][i][j]; others clamp to 48.
    const int lq = tid & 63;
    const int qq = (lq < 49) ? lq : 48;
    const int mk = qq / 7, mjj = qq - mk * 7;
    float Mv = 0.f;
    #pragma unroll
    for (int i2 = 0; i2 < LDIM; ++i2)
        Mv += raw_chol[mk * 49 + i2 * 7 + mjj];
    float mm[49];
    #pragma unroll
    for (int q = 0; q < 49; ++q) mm[q] = rlane(Mv, q);  // SGPR-resident

    // ---- stage betaT / rho / sd in LDS ----
    for (int i = tid; i < NF * KM1; i += BLOCK) {
        const int j = i / KM1, k = i - j * KM1;
        s_betaT[k][j] = beta[i];
    }
    if (tid < 64) {
        const int a = tid >> 3, c = tid & 7;
        if (a < LDIM) {
            float r = 0.f, sdv = 0.f;
            if (c < KM1) {
                r = tanhf(raw_rho[a * KM1 + c]);
                sdv = (1.0f / sqrtf(1.0f - r * r)) * raw_chol[c * 49 + a * 7 + a];
            }
            s_rho[a * 8 + c] = r;
            s_sd[a * 8 + c] = sdv;
        }
    }
    __syncthreads();

    const int r = tid >> 3;          // row within block
    const int p = tid & 7;           // lane-in-group: channel & step owner
    const int k_ld = (p < 6) ? p : 6;
    int n = blockIdx.x * RPB + r;
    const bool valid = (n < n_total);
    if (!valid) n = n_total - 1;

    const int b = batter_ids[n];
    const int l = league_ids[n];
    const int t = season_ids[n];

    // ---- fixed effects: acc = sum_j X[n,j] * beta[j, p] ----
    float acc = 0.f;
    {
        const float4* __restrict__ xrow =
            reinterpret_cast<const float4*>(X + (long)n * NF);
        const float4* __restrict__ brow =
            reinterpret_cast<const float4*>(&s_betaT[k_ld][0]);
        #pragma unroll 4
        for (int j4 = 0; j4 < NF / 4; ++j4) {
            const float4 x = xrow[j4];
            const float4 bb = brow[j4];
            acc = fmaf(x.x, bb.x, fmaf(x.y, bb.y,
                  fmaf(x.z, bb.z, fmaf(x.w, bb.w, acc))));
        }
    }

    // ---- rho row as 2 b128; rho_own by static extract ----
    float rho_all[KM1], r8[KM1];
    {
        const float4* rr = reinterpret_cast<const float4*>(&s_rho[l * 8]);
        const float4 ra = rr[0], rb = rr[1];
        rho_all[0] = ra.x; rho_all[1] = ra.y; rho_all[2] = ra.z;
        rho_all[3] = ra.w; rho_all[4] = rb.x; rho_all[5] = rb.y;
        rho_all[6] = rb.z;
    }
    #pragma unroll
    for (int j = 0; j < KM1; ++j) {
        const float r2 = rho_all[j] * rho_all[j];
        const float r4 = r2 * r2;
        r8[j] = r4 * r4;
    }
    float rho_own = rho_all[0];
    #pragma unroll
    for (int j = 1; j < KM1; ++j) rho_own = (k_ld == j) ? rho_all[j] : rho_own;

    const float* __restrict__ erow = eps + ((long)b * LDIM + l) * (TDIM * KM1);

    // ---- owned steps s = p+1+8i, FORWARD fold (earliest first) ----
    float q[KM1];
    #pragma unroll
    for (int j = 0; j < KM1; ++j) q[j] = 0.f;

    #pragma unroll
    for (int i = 0; i < 3; ++i) {
        const int s = p + 1 + 8 * i;
        if (s <= t) {                      // t<=19 so s<TDIM guaranteed
            float e[KM1];
            #pragma unroll
            for (int k = 0; k < KM1; ++k) e[k] = erow[s * KM1 + k];
            #pragma unroll
            for (int j = 0; j < KM1; ++j) {
                float nz = 0.f;
                #pragma unroll
                for (int k = 0; k < KM1; ++k)
                    nz = fmaf(e[k], mm[k * KM1 + j], nz);  // SGPR operand
                q[j] = fmaf(r8[j], q[j], nz);
            }
        }
    }

    // ---- scale by rho_j^((t-p-1)&7)  (q==0 when t<p+1, so &7 is safe) ----
    {
        const int m = (t - p - 1) & 7;
        float bs[KM1];
        #pragma unroll
        for (int j = 0; j < KM1; ++j) bs[j] = rho_all[j];
        #pragma unroll
        for (int bit = 0; bit < 3; ++bit) {
            const bool on = ((m >> bit) & 1) != 0;
            #pragma unroll
            for (int j = 0; j < KM1; ++j) {
                q[j] *= on ? bs[j] : 1.f;
                bs[j] *= bs[j];
            }
        }
    }

    // ---- butterfly-sum q over the 8-lane group ----
    #pragma unroll
    for (int j = 0; j < KM1; ++j) {
        q[j] += __shfl_xor(q[j], 1, 8);
        q[j] += __shfl_xor(q[j], 2, 8);
        q[j] += __shfl_xor(q[j], 4, 8);
    }
    // select own channel (static indices -> cndmask chain)
    float nzt = q[0];
    #pragma unroll
    for (int j = 1; j < KM1; ++j) nzt = (p == j) ? q[j] : nzt;

    // ---- e0 term: rho_own^t * sd * e0 ----
    const float e0 = erow[k_ld];
    const float sd = s_sd[l * 8 + k_ld];
    float pwt = 1.f;
    {
        float bo = rho_own;
        #pragma unroll
        for (int bit = 0; bit < 5; ++bit) {
            pwt *= (((t >> bit) & 1) != 0) ? bo : 1.f;
            bo *= bo;
        }
    }
    const float u = fmaf(pwt * sd, e0, nzt);
    const float last_e = erow[t * KM1 + k_ld];

    // ---- coalesced writes, no staging ----
    if (valid) {
        const int col = (p == 7) ? 0 : p + 1;
        out[(long)n * 8 + col] = (p == 7) ? 0.f : (acc + u);
        if (p < KM1)
            out[(long)n_total * 8 + (long)n * KM1 + p] = last_e;
    }
}

extern "C" void kernel_launch(void* const* d_in, const int* in_sizes, int n_in,
                              void* d_out, int out_size, void* d_ws, size_t ws_size,
                              hipStream_t stream)
{
    const float* X        = (const float*)d_in[0];
    const float* beta     = (const float*)d_in[1];
    const float* raw_rho  = (const float*)d_in[2];
    const float* raw_chol = (const float*)d_in[3];
    const float* eps      = (const float*)d_in[4];
    const int* batter_ids = (const int*)d_in[5];
    const int* league_ids = (const int*)d_in[6];
    const int* season_ids = (const int*)d_in[7];
    float* out = (float*)d_out;

    const int n_total = in_sizes[5];  // N = 200000
    const int grid = (n_total + RPB - 1) / RPB;

    hmr_kernel<<<grid, BLOCK, 0, stream>>>(X, beta, raw_rho, raw_chol, eps,
                                           batter_ids, league_ids, season_ids,
                                           out, n_total);
}